// Round 10
// baseline (921.365 us; speedup 1.0000x reference)
//
#include <hip/hip_runtime.h>
#include <cstdint>
#include <cstddef>

#define TSTEPS 512
#define INP    24
#define HID    128
#define BB     4      // batch elems per block; 256 blocks (1/CU)
#define NKT    5      // K = 24 x + 128 h + 8 pad = 160 = 5 tiles of 32
#define VSTR   168    // v[] column stride in fp16 elems

typedef __attribute__((ext_vector_type(8))) _Float16 half8;   // 8 x fp16 (4 VGPRs)
typedef __attribute__((ext_vector_type(4))) float f32x4;

__device__ __forceinline__ float sigm_f(float v) {
    return 1.0f / (1.0f + __expf(-v));
}
__device__ __forceinline__ float tanh_f(float v) {
    float a = fabsf(v);
    float e = __expf(-2.0f * a);
    float r = (1.0f - e) / (1.0f + e);
    return v < 0.0f ? -r : r;
}
__device__ __forceinline__ unsigned pack2h(float a, float b) {
    union { _Float16 h[2]; unsigned u; } z;
    z.h[0] = (_Float16)a; z.h[1] = (_Float16)b;
    return z.u;
}

// ROUND LESSONS ENCODED:
//  R1: VGPR-cap betrayal -> scratch spill shows as WRITE_SIZE GBs. Watch it.
//  R2: runtime-varying index into per-thread arrays demotes to memory.
//  R3: fp32 VALU ~3x too slow; use MFMA.
//  R4/R5: total time == per-block time. R6: mfma ~19.4 cyc/SIMD; phases sum.
//  R7/R8: LDS pipe is per-CU; layouts at conflict minimum.
//  R9: fp16 single-pass == bf16 2-pass accuracy (4.88e-4), half the drain.
//  R10 (this): "other" (~2100cyc) is the serial redistribution round-trip.
//      C-layout fact: lane (quad,ncol) holds ALL FOUR gates of units j0..j0+3,
//      batch ncol — redistribution through part_s only spreads ISSUE, which
//      exec masking doesn't save anyway. So: UPD in-register on all lanes
//      (4 independent chains, ILP; ncol>=4 results are garbage, never stored),
//      masked b64 h-write, ONE barrier/ts, part_s deleted. x-stagers moved to
//      wave 0 ncol>=4 lanes (disjoint from h-producers; xb=quad, kk=ncol-4).
//
// Per ts: gates[512 x 16] = W[512 x 160] @ v[160 x 16], batch cols 0..3 real.
// mfma_f32_16x16x32_f16: A-frag lane A[m=lane&15][k=quad*8+j];
// B-frag B[k=quad*8+j][n=lane&15]; C/D col=lane&15, row=quad*4+reg.
__global__ __launch_bounds__(512) __attribute__((amdgpu_waves_per_eu(2, 2)))
void lstm_fused(
    const float* __restrict__ x,      // [B, T, 24]
    const float* __restrict__ addin,  // [B, 2]
    const float* __restrict__ W_ih,   // [512, 24]
    const float* __restrict__ W_hh,   // [512, 128]
    const float* __restrict__ b_ih,   // [512]
    const float* __restrict__ b_hh,   // [512]
    const float* __restrict__ W1,     // [64, 130]
    const float* __restrict__ b1,     // [64]
    const float* __restrict__ W2,     // [3, 64]
    const float* __restrict__ b2,     // [3]
    float* __restrict__ out)          // [B, 3]
{
    __shared__ _Float16 v_s[2][16 * VSTR];   // [buf][n][k]; n>=BB stays 0
    __shared__ float z_s[BB][64];

    const int t    = threadIdx.x;      // 512 threads = 8 waves
    const int lane = t & 63;
    const int wv   = t >> 6;           // 0..7: owns unit rows wv*16..+15 (x4 gates)
    const int ncol = lane & 15;        // batch col (0..3 real)
    const int quad = lane >> 4;
    const int b0   = blockIdx.x * BB;
    const int j0   = wv * 16 + quad * 4;   // this lane's 4 units (C layout)

    // ---- persistent A-fragments (fp16) ----
    half8 A_w[4][NKT];
    #pragma unroll
    for (int g = 0; g < 4; ++g) {
        const int row = g * HID + wv * 16 + ncol;
        #pragma unroll
        for (int kt = 0; kt < NKT; ++kt) {
            half8 frag;
            #pragma unroll
            for (int j = 0; j < 8; ++j) {
                const int k = kt * 32 + quad * 8 + j;
                float w = 0.0f;
                if (k < INP)            w = W_ih[row * INP + k];
                else if (k < INP + HID) w = W_hh[row * HID + (k - INP)];
                frag[j] = (_Float16)w;
            }
            A_w[g][kt] = frag;
        }
    }

    // per-lane biases for units j0..j0+3 (accumulator initializers)
    const float4 bi4 = *(const float4*)(b_ih + 0 * HID + j0);
    const float4 bf4 = *(const float4*)(b_ih + 1 * HID + j0);
    const float4 bg4 = *(const float4*)(b_ih + 2 * HID + j0);
    const float4 bo4 = *(const float4*)(b_ih + 3 * HID + j0);
    const float4 ci4 = *(const float4*)(b_hh + 0 * HID + j0);
    const float4 cf4 = *(const float4*)(b_hh + 1 * HID + j0);
    const float4 cg4 = *(const float4*)(b_hh + 2 * HID + j0);
    const float4 co4 = *(const float4*)(b_hh + 3 * HID + j0);
    const f32x4 bias_i = {bi4.x + ci4.x, bi4.y + ci4.y, bi4.z + ci4.z, bi4.w + ci4.w};
    const f32x4 bias_f = {bf4.x + cf4.x, bf4.y + cf4.y, bf4.z + cf4.z, bf4.w + cf4.w};
    const f32x4 bias_g = {bg4.x + cg4.x, bg4.y + cg4.y, bg4.z + cg4.z, bg4.w + cg4.w};
    const f32x4 bias_o = {bo4.x + co4.x, bo4.y + co4.y, bo4.z + co4.z, bo4.w + co4.w};

    // x-stagers: wave 0, ncol>=4 (48 lanes, disjoint from h-producers)
    const bool stager = (wv == 0) && (ncol >= 4);
    const int xb = quad;              // batch 0..3
    const int kk = ncol - 4;          // k-pair 0..11

    // ---- init: zero both buffers (cols >= BB and pads stay 0), stage x(0) ----
    for (int i = t; i < 16 * VSTR; i += 512) {
        v_s[0][i] = (_Float16)0.0f; v_s[1][i] = (_Float16)0.0f;
    }
    __syncthreads();
    if (stager) {
        const float2 xv = *(const float2*)(x + ((size_t)(b0 + xb) * TSTEPS) * INP + kk * 2);
        *(unsigned*)&v_s[0][xb * VSTR + kk * 2] = pack2h(xv.x, xv.y);
    }
    // prime distance-2 x queue: xq = x(1)
    float2 xq = {0.f, 0.f};
    if (stager) {
        xq = *(const float2*)(x + ((size_t)(b0 + xb) * TSTEPS + 1) * INP + kk * 2);
    }
    f32x4 c_acc = {0.f, 0.f, 0.f, 0.f};   // cell state for units j0..j0+3, batch ncol
    __syncthreads();

    // ---- recurrence: ONE barrier per ts ----
    for (int ts = 0; ts < TSTEPS; ++ts) {
        const int pb = ts & 1, nb = pb ^ 1;

        // stagers: issue x(ts+2) load; stage x(ts+1)=xq into nb
        float2 xn = {0.f, 0.f};
        if (stager) {
            const int tsn = (ts + 2 < TSTEPS) ? ts + 2 : TSTEPS - 1;
            xn = *(const float2*)(x + ((size_t)(b0 + xb) * TSTEPS + tsn) * INP + kk * 2);
            *(unsigned*)&v_s[nb][xb * VSTR + kk * 2] = pack2h(xq.x, xq.y);
        }

        // MFMA phase: 5 kt x 4 gates = 20 mfma per wave, accs init from bias
        const _Float16* vh = v_s[pb];
        f32x4 ai = bias_i, af = bias_f, ag = bias_g, ao = bias_o;
        #pragma unroll
        for (int kt = 0; kt < NKT; ++kt) {
            const half8 bh = *(const half8*)(vh + ncol * VSTR + kt * 32 + quad * 8);
            ai = __builtin_amdgcn_mfma_f32_16x16x32_f16(A_w[0][kt], bh, ai, 0, 0, 0);
            af = __builtin_amdgcn_mfma_f32_16x16x32_f16(A_w[1][kt], bh, af, 0, 0, 0);
            ag = __builtin_amdgcn_mfma_f32_16x16x32_f16(A_w[2][kt], bh, ag, 0, 0, 0);
            ao = __builtin_amdgcn_mfma_f32_16x16x32_f16(A_w[3][kt], bh, ao, 0, 0, 0);
        }

        // in-register UPD on ALL lanes (4 independent chains; ncol>=4 = garbage,
        // never stored). Exec masking wouldn't reduce issue cost anyway.
        union { _Float16 h[4]; uint2 u; } hp;
        #define UPD(r)                                                         \
        {                                                                      \
            const float gi = sigm_f(ai[r]);                                    \
            const float gf = sigm_f(af[r]);                                    \
            const float gg = tanh_f(ag[r]);                                    \
            const float go = sigm_f(ao[r]);                                    \
            const float cnew = gf * c_acc[r] + gi * gg;                        \
            c_acc[r] = cnew;                                                   \
            hp.h[r] = (_Float16)(go * tanh_f(cnew));                           \
        }
        UPD(0) UPD(1) UPD(2) UPD(3)
        #undef UPD

        // masked h-write: batch ncol, units j0..j0+3 -> one b64
        if (ncol < BB) {
            *(uint2*)&v_s[nb][ncol * VSTR + INP + j0] = hp.u;
        }

        // roll x queue
        if (stager) xq = xn;
        __syncthreads();
    }

    // ---- FC head: final h is in buffer 0 (ts=511 -> nb=0); h is fp16 ----
    if (t < 256) {
        const int b = t >> 6, u = t & 63;
        const float* w = W1 + u * 130;
        float a = b1[u];
        #pragma unroll 16
        for (int k = 0; k < HID; ++k) {
            const float hv = (float)v_s[0][b * VSTR + INP + k];
            a += fmaxf(hv, 0.0f) * w[k];
        }
        const float a0 = addin[(size_t)(b0 + b) * 2 + 0];
        const float a1 = addin[(size_t)(b0 + b) * 2 + 1];
        a += fmaxf(a0, 0.0f) * w[128] + fmaxf(a1, 0.0f) * w[129];
        z_s[b][u] = fmaxf(a, 0.0f);
    }
    __syncthreads();
    if (t < 12) {
        const int b = t / 3, o = t - 3 * b;
        const float* w = W2 + o * 64;
        float a = b2[o];
        #pragma unroll
        for (int k = 0; k < 64; ++k)
            a += z_s[b][k] * w[k];
        out[(size_t)(b0 + b) * 3 + o] = a;
    }
}

extern "C" void kernel_launch(void* const* d_in, const int* in_sizes, int n_in,
                              void* d_out, int out_size, void* d_ws, size_t ws_size,
                              hipStream_t stream) {
    const float* x     = (const float*)d_in[0];
    const float* addin = (const float*)d_in[1];
    const float* W_ih  = (const float*)d_in[2];
    const float* W_hh  = (const float*)d_in[3];
    const float* b_ih  = (const float*)d_in[4];
    const float* b_hh  = (const float*)d_in[5];
    const float* W1    = (const float*)d_in[6];
    const float* b1    = (const float*)d_in[7];
    const float* W2    = (const float*)d_in[8];
    const float* b2    = (const float*)d_in[9];
    float* outp        = (float*)d_out;

    const int B = in_sizes[0] / (TSTEPS * INP);   // 1024
    const int grid = B / BB;                      // 256 blocks (1 per CU)

    lstm_fused<<<grid, 512, 0, stream>>>(x, addin, W_ih, W_hh, b_ih, b_hh,
                                         W1, b1, W2, b2, outp);
}

// Round 11
// 711.331 us; speedup vs baseline: 1.2953x; 1.2953x over previous
//
#include <hip/hip_runtime.h>
#include <cstdint>
#include <cstddef>

#define TSTEPS 512
#define INP    24
#define HID    128
#define BB     2      // batch elems per block; 512 blocks -> 2 blocks/CU (TLP)
#define NKT    5      // K = 24 x + 128 h + 8 pad = 160 = 5 tiles of 32
#define VSTR   168    // v[] column stride in fp16 elems
#define GB     520    // part_s batch stride in floats; %32==8 -> <=2-way banks

typedef __attribute__((ext_vector_type(8))) _Float16 half8;   // 8 x fp16 (4 VGPRs)
typedef __attribute__((ext_vector_type(4))) float f32x4;

__device__ __forceinline__ float rcp_f(float v) {
    return __builtin_amdgcn_rcpf(v);   // v_rcp_f32, ~1 ulp, 1 instr
}
__device__ __forceinline__ float sigm_f(float v) {
    return rcp_f(1.0f + __expf(-v));
}
__device__ __forceinline__ float tanh_f(float v) {
    float a = fabsf(v);
    float e = __expf(-2.0f * a);
    float r = (1.0f - e) * rcp_f(1.0f + e);
    return v < 0.0f ? -r : r;
}
__device__ __forceinline__ unsigned pack2h(float a, float b) {
    union { _Float16 h[2]; unsigned u; } z;
    z.h[0] = (_Float16)a; z.h[1] = (_Float16)b;
    return z.u;
}

// ROUND LESSONS ENCODED:
//  R1: VGPR-cap betrayal -> scratch spill shows as WRITE_SIZE GBs.
//  R2: runtime-varying index into per-thread arrays demotes to memory.
//  R3: fp32 VALU ~3x too slow; use MFMA. R6: mfma ~19.4 cyc/SIMD; phases sum.
//  R7/R8: LDS pipe is per-CU; layouts at conflict minimum.
//  R9: fp16 single-pass, 1-UPD-per-thread redistribution = best structure.
//  R10 FAILED: in-register UPD on all lanes = 4x VALU issue for same work
//      (only 16/64 lanes useful per chain). Redistribution PACKS scalar work
//      64-wide — lane-packing matters as much as barrier count. Reverted.
//  R11 (this): (a) BB=2, grid=512 -> 2 independent blocks/CU; per-block mfma
//      is BB-invariant so per-CU drain doubles, but the same 4 batches/CU are
//      served and the two blocks' serial chains interleave (stall-fill).
//      (b) v_rcp_f32 activations: UPD chain ~75 -> ~40 instrs.
//
// Per ts: gates[512 x 16] = W[512 x 160] @ v[160 x 16], batch cols 0..1 real.
// mfma_f32_16x16x32_f16: A-frag lane A[m=lane&15][k=quad*8+j];
// B-frag B[k=quad*8+j][n=lane&15]; C/D col=lane&15, row=quad*4+reg.
__global__ __launch_bounds__(512) __attribute__((amdgpu_waves_per_eu(4, 4)))
void lstm_fused(
    const float* __restrict__ x,      // [B, T, 24]
    const float* __restrict__ addin,  // [B, 2]
    const float* __restrict__ W_ih,   // [512, 24]
    const float* __restrict__ W_hh,   // [512, 128]
    const float* __restrict__ b_ih,   // [512]
    const float* __restrict__ b_hh,   // [512]
    const float* __restrict__ W1,     // [64, 130]
    const float* __restrict__ b1,     // [64]
    const float* __restrict__ W2,     // [3, 64]
    const float* __restrict__ b2,     // [3]
    float* __restrict__ out)          // [B, 3]
{
    __shared__ _Float16 v_s[2][16 * VSTR];   // [buf][n][k]; n>=BB stays 0
    __shared__ float part_s[BB * GB];        // [b][g*128+j] gate pre-acts
    __shared__ float z_s[BB][64];

    const int t    = threadIdx.x;      // 512 threads = 8 waves
    const int lane = t & 63;
    const int wv   = t >> 6;           // 0..7: owns unit rows wv*16..+15 (x4 gates)
    const int ncol = lane & 15;        // batch col (0..1 real)
    const int quad = lane >> 4;
    const int b0   = blockIdx.x * BB;
    const int j0   = wv * 16 + quad * 4;   // this lane's 4 unit-rows (C layout)

    // ---- persistent A-fragments (fp16) ----
    half8 A_w[4][NKT];
    #pragma unroll
    for (int g = 0; g < 4; ++g) {
        const int row = g * HID + wv * 16 + ncol;
        #pragma unroll
        for (int kt = 0; kt < NKT; ++kt) {
            half8 frag;
            #pragma unroll
            for (int j = 0; j < 8; ++j) {
                const int k = kt * 32 + quad * 8 + j;
                float w = 0.0f;
                if (k < INP)            w = W_ih[row * INP + k];
                else if (k < INP + HID) w = W_hh[row * HID + (k - INP)];
                frag[j] = (_Float16)w;
            }
            A_w[g][kt] = frag;
        }
    }

    // consumer role: threads t<256 own (batch ub = t>>7, unit uj = t&127)
    const int ub = t >> 7, uj = t & 127;     // ub valid for t<256
    const float bias_i = b_ih[0 * HID + uj] + b_hh[0 * HID + uj];
    const float bias_f = b_ih[1 * HID + uj] + b_hh[1 * HID + uj];
    const float bias_g = b_ih[2 * HID + uj] + b_hh[2 * HID + uj];
    const float bias_o = b_ih[3 * HID + uj] + b_hh[3 * HID + uj];
    float c_reg = 0.0f;

    // x-stagers: wave 0, quad<2, ncol>=4 -> 24 lanes; xb=quad, kk=ncol-4
    const bool stager = (wv == 0) && (quad < BB) && (ncol >= 4);
    const int xb = quad;
    const int kk = ncol - 4;

    // ---- init: zero both buffers (cols >= BB and pads stay 0), stage x(0) ----
    for (int i = t; i < 16 * VSTR; i += 512) {
        v_s[0][i] = (_Float16)0.0f; v_s[1][i] = (_Float16)0.0f;
    }
    __syncthreads();
    if (stager) {
        const float2 xv = *(const float2*)(x + ((size_t)(b0 + xb) * TSTEPS) * INP + kk * 2);
        *(unsigned*)&v_s[0][xb * VSTR + kk * 2] = pack2h(xv.x, xv.y);
    }
    // prime distance-2 x queue: xq = x(1)
    float2 xq = {0.f, 0.f};
    if (stager) {
        xq = *(const float2*)(x + ((size_t)(b0 + xb) * TSTEPS + 1) * INP + kk * 2);
    }
    __syncthreads();

    // ---- recurrence: 2 barriers per ts (redistribution) ----
    for (int ts = 0; ts < TSTEPS; ++ts) {
        const int pb = ts & 1, nb = pb ^ 1;

        // top: issue x(ts+2) load; stage x(ts+1)=xq into nb (read only next ts)
        float2 xn = {0.f, 0.f};
        if (stager) {
            const int tsn = (ts + 2 < TSTEPS) ? ts + 2 : TSTEPS - 1;
            xn = *(const float2*)(x + ((size_t)(b0 + xb) * TSTEPS + tsn) * INP + kk * 2);
            *(unsigned*)&v_s[nb][xb * VSTR + kk * 2] = pack2h(xq.x, xq.y);
        }

        // MFMA phase: 5 kt x 4 gates = 20 mfma per wave
        const _Float16* vh = v_s[pb];
        f32x4 ai = {0.f, 0.f, 0.f, 0.f}, af = ai, ag = ai, ao = ai;
        #pragma unroll
        for (int kt = 0; kt < NKT; ++kt) {
            const half8 bh = *(const half8*)(vh + ncol * VSTR + kt * 32 + quad * 8);
            ai = __builtin_amdgcn_mfma_f32_16x16x32_f16(A_w[0][kt], bh, ai, 0, 0, 0);
            af = __builtin_amdgcn_mfma_f32_16x16x32_f16(A_w[1][kt], bh, af, 0, 0, 0);
            ag = __builtin_amdgcn_mfma_f32_16x16x32_f16(A_w[2][kt], bh, ag, 0, 0, 0);
            ao = __builtin_amdgcn_mfma_f32_16x16x32_f16(A_w[3][kt], bh, ao, 0, 0, 0);
        }

        // producer: publish gate pre-acts for real batch cols (f32x4, <=2-way banks)
        if (ncol < BB) {
            float* gp = part_s + ncol * GB + j0;
            *(f32x4*)(gp + 0 * HID) = ai;
            *(f32x4*)(gp + 1 * HID) = af;
            *(f32x4*)(gp + 2 * HID) = ag;
            *(f32x4*)(gp + 3 * HID) = ao;
        }
        __syncthreads();

        // consumer: ONE cell update per thread, t<256 (= BB*HID pairs)
        if (t < BB * HID) {
            const float gi = sigm_f(part_s[ub * GB + 0 * HID + uj] + bias_i);
            const float gf = sigm_f(part_s[ub * GB + 1 * HID + uj] + bias_f);
            const float gg = tanh_f(part_s[ub * GB + 2 * HID + uj] + bias_g);
            const float go = sigm_f(part_s[ub * GB + 3 * HID + uj] + bias_o);
            c_reg = gf * c_reg + gi * gg;
            const float h = go * tanh_f(c_reg);
            v_s[nb][ub * VSTR + INP + uj] = (_Float16)h;
        }

        // roll x queue
        if (stager) xq = xn;
        __syncthreads();
    }

    // ---- FC head: final h is in buffer 0 (ts=511 -> nb=0); h is fp16 ----
    if (t < BB * 64) {
        const int b = t >> 6, u = t & 63;
        const float* w = W1 + u * 130;
        float a = b1[u];
        #pragma unroll 16
        for (int k = 0; k < HID; ++k) {
            const float hv = (float)v_s[0][b * VSTR + INP + k];
            a += fmaxf(hv, 0.0f) * w[k];
        }
        const float a0 = addin[(size_t)(b0 + b) * 2 + 0];
        const float a1 = addin[(size_t)(b0 + b) * 2 + 1];
        a += fmaxf(a0, 0.0f) * w[128] + fmaxf(a1, 0.0f) * w[129];
        z_s[b][u] = fmaxf(a, 0.0f);
    }
    __syncthreads();
    if (t < BB * 3) {
        const int b = t / 3, o = t - 3 * b;
        const float* w = W2 + o * 64;
        float a = b2[o];
        #pragma unroll
        for (int k = 0; k < 64; ++k)
            a += z_s[b][k] * w[k];
        out[(size_t)(b0 + b) * 3 + o] = a;
    }
}

extern "C" void kernel_launch(void* const* d_in, const int* in_sizes, int n_in,
                              void* d_out, int out_size, void* d_ws, size_t ws_size,
                              hipStream_t stream) {
    const float* x     = (const float*)d_in[0];
    const float* addin = (const float*)d_in[1];
    const float* W_ih  = (const float*)d_in[2];
    const float* W_hh  = (const float*)d_in[3];
    const float* b_ih  = (const float*)d_in[4];
    const float* b_hh  = (const float*)d_in[5];
    const float* W1    = (const float*)d_in[6];
    const float* b1    = (const float*)d_in[7];
    const float* W2    = (const float*)d_in[8];
    const float* b2    = (const float*)d_in[9];
    float* outp        = (float*)d_out;

    const int B = in_sizes[0] / (TSTEPS * INP);   // 1024
    const int grid = B / BB;                      // 512 blocks -> 2 per CU

    lstm_fused<<<grid, 512, 0, stream>>>(x, addin, W_ih, W_hh, b_ih, b_hh,
                                         W1, b1, W2, b2, outp);
}